// Round 3
// baseline (7412.183 us; speedup 1.0000x reference)
//
#include <hip/hip_runtime.h>
#include <hip/hip_bf16.h>
#include <stdint.h>

typedef __attribute__((ext_vector_type(8))) short bf16x8;
typedef __attribute__((ext_vector_type(4))) float f32x4;
typedef __attribute__((ext_vector_type(4))) int int4v;
typedef unsigned long long u64;

#define DD 512
#define HH 512
#define BB 32

__device__ __forceinline__ unsigned short f2bf(float f) {
  unsigned u = __float_as_uint(f);
  u += 0x7fffu + ((u >> 16) & 1u);
  return (unsigned short)(u >> 16);
}
__device__ __forceinline__ float sigf(float x) { return 1.f / (1.f + __expf(-x)); }
__device__ __forceinline__ float tanhfast(float x) {
  float e = __expf(fminf(fmaxf(2.f * x, -60.f), 60.f));
  return (e - 1.f) / (e + 1.f);
}

// ---- init kernels ----
// hbuf: u64 entries, [g(2)][parity(2)][m(16)][pair(256)]; value = tag<<32 | 2xbf16
__global__ void init_state(u64* hbuf, const float* __restrict__ h0, int* L) {
  int i = blockIdx.x * blockDim.x + threadIdx.x;
  if (i < 32) L[i] = 0;
  if (i < 16384) {
    int g = i >> 13, p = (i >> 12) & 1, m = (i >> 8) & 15, q = i & 255;
    u64 v;
    if (p == 0) {
      int b = g * 16 + m;
      unsigned lo = f2bf(h0[(size_t)b * HH + 2 * q]);
      unsigned hi = f2bf(h0[(size_t)b * HH + 2 * q + 1]);
      v = (u64)(lo | (hi << 16));              // tag = 0 (step 0)
    } else {
      v = 0xFFFFFFFF00000000ull;               // tag that never matches
    }
    hbuf[i] = v;
  }
}

__global__ void init_idx(const int* __restrict__ t_idx, const int* __restrict__ b_idx,
                         int* rowstart, int* L, int total) {
  int r = blockIdx.x * blockDim.x + threadIdx.x;
  if (r >= total) return;
  int t = t_idx[r];
  if (r == 0 || t_idx[r - 1] != t) rowstart[t] = r;
  atomicMax(&L[b_idx[r]], t + 1);
}

// ---- main persistent recurrent kernel ----
// 64 blocks. bid = [k_hi(3b)][g(1b)][k_lo(2b)] so group 0 -> XCDs 0-3, group 1 -> XCDs 4-7.
__global__ __launch_bounds__(256, 1)
void lstm_main(const float* __restrict__ X, const float* __restrict__ h0,
               const float* __restrict__ c0, const float* __restrict__ w_ih,
               const float* __restrict__ w_hh, const float* __restrict__ b_ih,
               const float* __restrict__ b_hh, const int* __restrict__ rowstart,
               const int* __restrict__ L, u64* hbuf,
               float* out, int total)
{
  const int tid = threadIdx.x;
  const int bid = blockIdx.x;
  const int g = (bid >> 2) & 1;
  const int k = (bid & 3) | ((bid >> 3) << 2);
  const int lane = tid & 63;
  const int wave = tid >> 6;      // wave = gate type (i,f,g,o)
  const int ul = lane & 15;       // MFMA row (m) for A, col for B/C
  const int kc = lane >> 4;       // 0..3
  const int u0 = k * 16;
  const int j = wave * 512 + u0 + ul;   // gate column in [0,2048)

  __shared__ unsigned short h_st[16 * DD];   // 16KB, swizzled rows
  __shared__ unsigned short x_st[16 * DD];   // 16KB, swizzled rows
  __shared__ float gl[4][16][16];            // gates exchange

  // ---- preload weights into registers as bf16 B-fragments ----
  bf16x8 wfa[16], wfb[16];
#pragma unroll
  for (int kk = 0; kk < 16; kk++) {
    const float* pa = w_ih + (size_t)j * DD + kk * 32 + kc * 8;
    const float* pb = w_hh + (size_t)j * DD + kk * 32 + kc * 8;
    bf16x8 va, vb;
#pragma unroll
    for (int e = 0; e < 8; e++) { va[e] = (short)f2bf(pa[e]); vb[e] = (short)f2bf(pb[e]); }
    wfa[kk] = va; wfb[kk] = vb;
  }
  const float bias = b_ih[j] + b_hh[j];

  // ---- cell-thread mapping: thread -> (m, u) ----
  const int mC = tid >> 4;
  const int uC = tid & 15;
  const int bcell = g * 16 + mC;
  const int Lc = L[bcell];
  float c_reg = c0[(size_t)bcell * HH + u0 + uC];
  const float c0c = c_reg;
  const float h0c = h0[(size_t)bcell * HH + u0 + uC];

  int t0 = 0;
#pragma unroll
  for (int m = 0; m < 16; m++) t0 = max(t0, L[g * 16 + m]);
  t0 -= 1;
  const int S = t0 + 1;

  u64* hb_g = hbuf + g * 8192;               // [2 parity][16 m][256 tagged pairs]
  const size_t hT_off = (size_t)total * HH;
  const size_t cT_off = hT_off + (size_t)BB * HH;

  char* hst_c = (char*)h_st;
  char* xst_c = (char*)x_st;
  const int swzW = (mC & 7) << 4;             // write-side XOR swizzle
  const int rbase = mC * 1024 + uC * 64;      // this thread's 64B region in stage
  const int arow = ul * 1024;
  const int aswz = (ul & 7) << 4;             // read-side XOR swizzle

  // prologue: x registers for the first step
  f32x4 xr[8];
  {
    const bool a0 = (t0 < Lc);
    if (a0) {
      const f32x4* xp = (const f32x4*)(X + (size_t)(rowstart[t0] + bcell) * DD + uC * 32);
#pragma unroll
      for (int q = 0; q < 8; q++) xr[q] = xp[q];
    } else {
#pragma unroll
      for (int q = 0; q < 8; q++) xr[q] = (f32x4){0.f, 0.f, 0.f, 0.f};
    }
  }

  for (int s = 0, t = t0; s < S; s++, t--) {
    const bool act = (t < Lc);
    // 1) stage x from registers (no global latency here)
#pragma unroll
    for (int c = 0; c < 4; c++) {
      f32x4 a = xr[2 * c], b2 = xr[2 * c + 1];
      int4v ch = {(int)(f2bf(a[0]) | ((unsigned)f2bf(a[1]) << 16)),
                  (int)(f2bf(a[2]) | ((unsigned)f2bf(a[3]) << 16)),
                  (int)(f2bf(b2[0]) | ((unsigned)f2bf(b2[1]) << 16)),
                  (int)(f2bf(b2[2]) | ((unsigned)f2bf(b2[3]) << 16))};
      *(int4v*)(xst_c + ((rbase + c * 16) ^ swzW)) = ch;
    }
    __syncthreads();   // B1: x_st ready

    // 2) issue the tagged h-gather (doubles as the sync poll)
    const u64* src = hb_g + (size_t)((s & 1) * 4096) + mC * 256 + uC * 16;
    u64 hv[16];
#pragma unroll
    for (int q = 0; q < 16; q++)
      hv[q] = __hip_atomic_load(src + q, __ATOMIC_RELAXED, __HIP_MEMORY_SCOPE_AGENT);

    // 3) prefetch next step's x into registers (latency hidden under poll+compute)
    {
      bool nact = false;
      if (t > 0) {
        nact = ((t - 1) < Lc);
        if (nact) {
          const f32x4* xp = (const f32x4*)(X + (size_t)(rowstart[t - 1] + bcell) * DD + uC * 32);
#pragma unroll
          for (int q = 0; q < 8; q++) xr[q] = xp[q];
        }
      }
      if (!nact) {
#pragma unroll
        for (int q = 0; q < 8; q++) xr[q] = (f32x4){0.f, 0.f, 0.f, 0.f};
      }
    }

    // 4) x-part MFMAs — overlap the gather round trip
    f32x4 C = {bias, bias, bias, bias};
#pragma unroll
    for (int kk = 0; kk < 16; kk++) {
      bf16x8 A = *(const bf16x8*)(xst_c + ((arow + kk * 64 + kc * 16) ^ aswz));
      C = __builtin_amdgcn_mfma_f32_16x16x32_bf16(A, wfa[kk], C, 0, 0, 0);
    }

    // 5) tag check + retry (the only wait in the handshake)
    const unsigned want = (unsigned)s;
    for (;;) {
      bool ok = true;
#pragma unroll
      for (int q = 0; q < 16; q++) ok &= ((unsigned)(hv[q] >> 32) == want);
      if (ok) break;
#pragma unroll
      for (int q = 0; q < 16; q++)
        hv[q] = __hip_atomic_load(src + q, __ATOMIC_RELAXED, __HIP_MEMORY_SCOPE_AGENT);
    }

    // 6) stage h -> swizzled LDS
#pragma unroll
    for (int c = 0; c < 4; c++) {
      int4v ch = {(int)(unsigned)hv[4 * c], (int)(unsigned)hv[4 * c + 1],
                  (int)(unsigned)hv[4 * c + 2], (int)(unsigned)hv[4 * c + 3]};
      *(int4v*)(hst_c + ((rbase + c * 16) ^ swzW)) = ch;
    }
    __syncthreads();   // B2: h_st ready

    // 7) h-part MFMAs, two chains to shorten the dependent tail
    f32x4 C2 = {0.f, 0.f, 0.f, 0.f};
#pragma unroll
    for (int kk = 0; kk < 8; kk++) {
      bf16x8 A0 = *(const bf16x8*)(hst_c + ((arow + (2 * kk) * 64 + kc * 16) ^ aswz));
      bf16x8 A1 = *(const bf16x8*)(hst_c + ((arow + (2 * kk + 1) * 64 + kc * 16) ^ aswz));
      C  = __builtin_amdgcn_mfma_f32_16x16x32_bf16(A0, wfb[2 * kk], C, 0, 0, 0);
      C2 = __builtin_amdgcn_mfma_f32_16x16x32_bf16(A1, wfb[2 * kk + 1], C2, 0, 0, 0);
    }
#pragma unroll
    for (int r = 0; r < 4; r++) C[r] += C2[r];

    // 8) exchange gates across waves (C/D layout: col=lane&15, row=(lane>>4)*4+r)
#pragma unroll
    for (int r = 0; r < 4; r++) gl[wave][kc * 4 + r][ul] = C[r];
    __syncthreads();   // B3

    // 9) cell math (fp32, c state thread-resident)
    float gi = gl[0][mC][uC], gf = gl[1][mC][uC], gg = gl[2][mC][uC], go = gl[3][mC][uC];
    float iv = sigf(gi), fv = sigf(gf), gv = tanhfast(gg), ov = sigf(go);
    float cn = fv * c_reg + iv * gv;
    float hn = ov * tanhfast(cn);
    float hp = act ? hn : h0c;     // inactive: keep publishing h0 (matches mask reset)
    c_reg = act ? cn : c0c;

    // 10) publish tagged pairs immediately — no drain, no flag
    {
      unsigned hbf = (unsigned)f2bf(hp);
      unsigned v1 = __shfl_down(hbf, 1);
      if ((uC & 1) == 0) {
        u64 val = ((u64)(unsigned)(s + 1) << 32) | (hbf & 0xffffu) | ((v1 & 0xffffu) << 16);
        u64* dst = hb_g + (size_t)(((s + 1) & 1) * 4096) + mC * 256 + k * 8 + (uC >> 1);
        __hip_atomic_store(dst, val, __ATOMIC_RELAXED, __HIP_MEMORY_SCOPE_AGENT);
      }
    }

    // 11) output stores, off the critical path
    if (act) {
      const int rst = rowstart[t];
      out[(size_t)(rst + bcell) * HH + u0 + uC] = hn;
      if (t == 0) {
        out[hT_off + (size_t)bcell * HH + u0 + uC] = hn;
        out[cT_off + (size_t)bcell * HH + u0 + uC] = cn;
      }
    }
  }
}

extern "C" void kernel_launch(void* const* d_in, const int* in_sizes, int n_in,
                              void* d_out, int out_size, void* d_ws, size_t ws_size,
                              hipStream_t stream) {
  const float* X    = (const float*)d_in[0];
  const float* h0   = (const float*)d_in[1];
  const float* c0   = (const float*)d_in[2];
  const float* w_ih = (const float*)d_in[3];
  const float* w_hh = (const float*)d_in[4];
  const float* b_ih = (const float*)d_in[5];
  const float* b_hh = (const float*)d_in[6];
  const int* t_idx  = (const int*)d_in[7];
  const int* b_idx  = (const int*)d_in[8];
  int total = in_sizes[0] / DD;

  // ws layout: hbuf (16384 u64 = 128KB) | rowstart (2048 int) | L (32 int)
  u64* hbuf     = (u64*)d_ws;
  int* rowstart = (int*)((char*)d_ws + 131072);
  int* L        = rowstart + 2048;

  hipLaunchKernelGGL(init_state, dim3(64), dim3(256), 0, stream, hbuf, h0, L);
  hipLaunchKernelGGL(init_idx, dim3((total + 255) / 256), dim3(256), 0, stream,
                     t_idx, b_idx, rowstart, L, total);
  hipLaunchKernelGGL(lstm_main, dim3(64), dim3(256), 0, stream,
                     X, h0, c0, w_ih, w_hh, b_ih, b_hh, rowstart, L, hbuf,
                     (float*)d_out, total);
}

// Round 4
// 4521.445 us; speedup vs baseline: 1.6393x; 1.6393x over previous
//
#include <hip/hip_runtime.h>
#include <hip/hip_bf16.h>
#include <stdint.h>

typedef __attribute__((ext_vector_type(8))) short bf16x8;
typedef __attribute__((ext_vector_type(4))) float f32x4;
typedef __attribute__((ext_vector_type(4))) int int4v;
typedef unsigned long long u64;

#define DD 512
#define HH 512
#define BB 32

__device__ __forceinline__ unsigned short f2bf(float f) {
  unsigned u = __float_as_uint(f);
  u += 0x7fffu + ((u >> 16) & 1u);
  return (unsigned short)(u >> 16);
}
__device__ __forceinline__ int pk2(float a, float b) {
  return (int)((unsigned)f2bf(a) | ((unsigned)f2bf(b) << 16));
}
__device__ __forceinline__ float sigf(float x) { return 1.f / (1.f + __expf(-x)); }
__device__ __forceinline__ float tanhfast(float x) {
  float e = __expf(fminf(fmaxf(2.f * x, -60.f), 60.f));
  return (e - 1.f) / (e + 1.f);
}

// ---- init kernels ----
// hbuf: u64 entries, [g(2)][parity(2)][row(16)][pair(256)]; value = tag<<32 | 2xbf16
__global__ void init_state(u64* hbuf, const float* __restrict__ h0, int* L) {
  int i = blockIdx.x * blockDim.x + threadIdx.x;
  if (i < 32) L[i] = 0;
  if (i < 16384) {
    int g = i >> 13, p = (i >> 12) & 1, m = (i >> 8) & 15, q = i & 255;
    u64 v;
    if (p == 0) {
      int b = g * 16 + m;
      unsigned lo = f2bf(h0[(size_t)b * HH + 2 * q]);
      unsigned hi = f2bf(h0[(size_t)b * HH + 2 * q + 1]);
      v = (u64)(lo | (hi << 16));              // tag = 0 (step 0)
    } else {
      v = 0xFFFFFFFF00000000ull;               // tag that never matches
    }
    hbuf[i] = v;
  }
}

__global__ void init_idx(const int* __restrict__ t_idx, const int* __restrict__ b_idx,
                         int* rowstart, int* L, int total) {
  int r = blockIdx.x * blockDim.x + threadIdx.x;
  if (r >= total) return;
  int t = t_idx[r];
  if (r == 0 || t_idx[r - 1] != t) rowstart[t] = r;
  atomicMax(&L[b_idx[r]], t + 1);
}

// ---- main persistent recurrent kernel ----
// 32 blocks x 512 threads. g = bid&1 (16 seqs), k = bid>>1 (32 hidden units).
// Degree-16 all-to-all per group (was 32).
__global__ __launch_bounds__(512, 2)
void lstm_main(const float* __restrict__ X, const float* __restrict__ h0,
               const float* __restrict__ c0, const float* __restrict__ w_ih,
               const float* __restrict__ w_hh, const float* __restrict__ b_ih,
               const float* __restrict__ b_hh, const int* __restrict__ rowstart,
               const int* __restrict__ L, u64* hbuf,
               float* out, int total)
{
  const int tid = threadIdx.x;
  const int bid = blockIdx.x;
  const int g = bid & 1;
  const int k = bid >> 1;            // [0,16)
  const int lane = tid & 63;
  const int wave = tid >> 6;         // [0,8)
  const int gate = wave & 3;         // i,f,g,o
  const int cs = wave >> 2;          // which 16-col half of the 32-unit slice
  const int ul = lane & 15;
  const int kc = lane >> 4;          // 0..3
  const int u0 = k * 32;
  const int j = gate * 512 + u0 + cs * 16 + ul;   // gate column in [0,2048)

  __shared__ unsigned short h_st[16 * DD];   // 16KB, swizzled rows
  __shared__ unsigned short x_st[16 * DD];   // 16KB, swizzled rows
  __shared__ float gl[4][16][32];            // gates exchange (8KB)

  // ---- resident weights: bf16 B-fragments for this wave's 16-col j-slice ----
  bf16x8 wfa[16], wfb[16];
#pragma unroll
  for (int kk = 0; kk < 16; kk++) {
    const float* pa = w_ih + (size_t)j * DD + kk * 32 + kc * 8;
    const float* pb = w_hh + (size_t)j * DD + kk * 32 + kc * 8;
    bf16x8 va, vb;
#pragma unroll
    for (int e = 0; e < 8; e++) { va[e] = (short)f2bf(pa[e]); vb[e] = (short)f2bf(pb[e]); }
    wfa[kk] = va; wfb[kk] = vb;
  }
  const float bias = b_ih[j] + b_hh[j];

  // ---- cell-thread mapping: thread -> (seq row mC, unit uC) ----
  const int mC = tid >> 5;           // [0,16)
  const int uC = tid & 31;           // [0,32)
  const int bcell = g * 16 + mC;
  const int Lc = L[bcell];
  float c_reg = c0[(size_t)bcell * HH + u0 + uC];
  const float c0c = c_reg;
  const float h0c = h0[(size_t)bcell * HH + u0 + uC];

  int t0 = 0;
#pragma unroll
  for (int m = 0; m < 16; m++) t0 = max(t0, L[g * 16 + m]);
  t0 -= 1;
  const int S = t0 + 1;

  u64* hb_g = hbuf + g * 8192;       // [2 parity][16 row][256 tagged pairs]
  const size_t hT_off = (size_t)total * HH;
  const size_t cT_off = hT_off + (size_t)BB * HH;

  char* hst_c = (char*)h_st;
  char* xst_c = (char*)x_st;
  // gather rotation (bijective per block): spread consumers across lines
  const int gr = (mC + k) & 15;      // source row
  const int gc = (uC + 2 * k) & 31;  // source 8-pair chunk
  const int hbyte = gr * 1024 + gc * 32, hsw = (gr & 7) << 4;
  const int xbyte = mC * 1024 + uC * 32, xsw = (mC & 7) << 4;
  const int arow = ul * 1024, aswz = (ul & 7) << 4;

  // prologue: x registers for the first step (row mC, 16 floats per thread)
  f32x4 xr[4];
  {
    if (t0 < Lc) {
      const f32x4* xp = (const f32x4*)(X + (size_t)(rowstart[t0] + bcell) * DD + uC * 16);
#pragma unroll
      for (int q = 0; q < 4; q++) xr[q] = xp[q];
    } else {
#pragma unroll
      for (int q = 0; q < 4; q++) xr[q] = (f32x4){0.f, 0.f, 0.f, 0.f};
    }
  }

  for (int s = 0, t = t0; s < S; s++, t--) {
    const bool act = (t < Lc);
    // 1) stage x from registers
    {
      int4v e0 = {pk2(xr[0][0], xr[0][1]), pk2(xr[0][2], xr[0][3]),
                  pk2(xr[1][0], xr[1][1]), pk2(xr[1][2], xr[1][3])};
      int4v e1 = {pk2(xr[2][0], xr[2][1]), pk2(xr[2][2], xr[2][3]),
                  pk2(xr[3][0], xr[3][1]), pk2(xr[3][2], xr[3][3])};
      *(int4v*)(xst_c + (xbyte ^ xsw)) = e0;
      *(int4v*)(xst_c + ((xbyte + 16) ^ xsw)) = e1;
    }
    __syncthreads();   // B1: x_st ready

    // 2) issue the tagged h-gather: 4 coherent dwordx4 (2 tagged pairs each)
    const u64* src = hb_g + (size_t)((s & 1) * 4096) + gr * 256 + gc * 8;
    int4v c0v, c1v, c2v, c3v;
    asm volatile(
      "global_load_dwordx4 %0, %4, off sc0 sc1\n\t"
      "global_load_dwordx4 %1, %5, off sc0 sc1\n\t"
      "global_load_dwordx4 %2, %6, off sc0 sc1\n\t"
      "global_load_dwordx4 %3, %7, off sc0 sc1"
      : "=&v"(c0v), "=&v"(c1v), "=&v"(c2v), "=&v"(c3v)
      : "v"(src), "v"(src + 2), "v"(src + 4), "v"(src + 6)
      : "memory");

    // 3) x-part MFMAs — overlap the gather round trip
    f32x4 C = {bias, bias, bias, bias};
#pragma unroll
    for (int kk = 0; kk < 16; kk++) {
      bf16x8 A = *(const bf16x8*)(xst_c + ((arow + kk * 64 + kc * 16) ^ aswz));
      C = __builtin_amdgcn_mfma_f32_16x16x32_bf16(A, wfa[kk], C, 0, 0, 0);
    }

    // 4) detect: per-8B self-validating tags; bounded spin w/ atomic fallback
    asm volatile("s_waitcnt vmcnt(0)" ::: "memory");
    __builtin_amdgcn_sched_barrier(0);
    const unsigned want = (unsigned)s;
    int spins = 0;
    while (!(((unsigned)c0v[1] == want) & ((unsigned)c0v[3] == want) &
             ((unsigned)c1v[1] == want) & ((unsigned)c1v[3] == want) &
             ((unsigned)c2v[1] == want) & ((unsigned)c2v[3] == want) &
             ((unsigned)c3v[1] == want) & ((unsigned)c3v[3] == want))) {
      if (++spins < 4096) {
        asm volatile(
          "global_load_dwordx4 %0, %4, off sc0 sc1\n\t"
          "global_load_dwordx4 %1, %5, off sc0 sc1\n\t"
          "global_load_dwordx4 %2, %6, off sc0 sc1\n\t"
          "global_load_dwordx4 %3, %7, off sc0 sc1\n\t"
          "s_waitcnt vmcnt(0)"
          : "=&v"(c0v), "=&v"(c1v), "=&v"(c2v), "=&v"(c3v)
          : "v"(src), "v"(src + 2), "v"(src + 4), "v"(src + 6)
          : "memory");
        __builtin_amdgcn_sched_barrier(0);
      } else {
        u64 a0 = __hip_atomic_load(src + 0, __ATOMIC_RELAXED, __HIP_MEMORY_SCOPE_AGENT);
        u64 a1 = __hip_atomic_load(src + 1, __ATOMIC_RELAXED, __HIP_MEMORY_SCOPE_AGENT);
        u64 a2 = __hip_atomic_load(src + 2, __ATOMIC_RELAXED, __HIP_MEMORY_SCOPE_AGENT);
        u64 a3 = __hip_atomic_load(src + 3, __ATOMIC_RELAXED, __HIP_MEMORY_SCOPE_AGENT);
        u64 a4 = __hip_atomic_load(src + 4, __ATOMIC_RELAXED, __HIP_MEMORY_SCOPE_AGENT);
        u64 a5 = __hip_atomic_load(src + 5, __ATOMIC_RELAXED, __HIP_MEMORY_SCOPE_AGENT);
        u64 a6 = __hip_atomic_load(src + 6, __ATOMIC_RELAXED, __HIP_MEMORY_SCOPE_AGENT);
        u64 a7 = __hip_atomic_load(src + 7, __ATOMIC_RELAXED, __HIP_MEMORY_SCOPE_AGENT);
        c0v = (int4v){(int)a0, (int)(a0 >> 32), (int)a1, (int)(a1 >> 32)};
        c1v = (int4v){(int)a2, (int)(a2 >> 32), (int)a3, (int)(a3 >> 32)};
        c2v = (int4v){(int)a4, (int)(a4 >> 32), (int)a5, (int)(a5 >> 32)};
        c3v = (int4v){(int)a6, (int)(a6 >> 32), (int)a7, (int)(a7 >> 32)};
      }
    }

    // 5) prefetch next step's x (AFTER detect: keeps HBM latency out of the wait)
    {
      bool nact = false;
      if (t > 0) {
        nact = ((t - 1) < Lc);
        if (nact) {
          const f32x4* xp = (const f32x4*)(X + (size_t)(rowstart[t - 1] + bcell) * DD + uC * 16);
#pragma unroll
          for (int q = 0; q < 4; q++) xr[q] = xp[q];
        }
      }
      if (!nact) {
#pragma unroll
        for (int q = 0; q < 4; q++) xr[q] = (f32x4){0.f, 0.f, 0.f, 0.f};
      }
    }

    // 6) stage h -> swizzled LDS (strip tags)
    {
      int4v d0 = {c0v[0], c0v[2], c1v[0], c1v[2]};
      int4v d1 = {c2v[0], c2v[2], c3v[0], c3v[2]};
      *(int4v*)(hst_c + (hbyte ^ hsw)) = d0;
      *(int4v*)(hst_c + ((hbyte + 16) ^ hsw)) = d1;
    }
    __syncthreads();   // B2: h_st ready

    // 7) h-part MFMAs, two chains to shorten the dependent tail
    f32x4 C2 = {0.f, 0.f, 0.f, 0.f};
#pragma unroll
    for (int kk = 0; kk < 8; kk++) {
      bf16x8 A0 = *(const bf16x8*)(hst_c + ((arow + (2 * kk) * 64 + kc * 16) ^ aswz));
      bf16x8 A1 = *(const bf16x8*)(hst_c + ((arow + (2 * kk + 1) * 64 + kc * 16) ^ aswz));
      C  = __builtin_amdgcn_mfma_f32_16x16x32_bf16(A0, wfb[2 * kk], C, 0, 0, 0);
      C2 = __builtin_amdgcn_mfma_f32_16x16x32_bf16(A1, wfb[2 * kk + 1], C2, 0, 0, 0);
    }
#pragma unroll
    for (int r = 0; r < 4; r++) C[r] += C2[r];

    // 8) exchange gates (C/D layout: col=lane&15, row=(lane>>4)*4+r)
#pragma unroll
    for (int r = 0; r < 4; r++) gl[gate][kc * 4 + r][cs * 16 + ul] = C[r];
    __syncthreads();   // B3

    // 9) cell math (fp32, c state thread-resident)
    float gi = gl[0][mC][uC], gf = gl[1][mC][uC], gg = gl[2][mC][uC], go = gl[3][mC][uC];
    float iv = sigf(gi), fv = sigf(gf), gv = tanhfast(gg), ov = sigf(go);
    float cn = fv * c_reg + iv * gv;
    float hn = ov * tanhfast(cn);
    float hp = act ? hn : h0c;     // inactive: republish h0 (matches mask reset)
    c_reg = act ? cn : c0c;

    // 10) publish tagged pairs (atomic u64, proven path; only 256/block)
    {
      unsigned hbf = (unsigned)f2bf(hp);
      unsigned v1 = __shfl_down(hbf, 1);
      if ((uC & 1) == 0) {
        u64 val = ((u64)(unsigned)(s + 1) << 32) | (hbf & 0xffffu) | ((v1 & 0xffffu) << 16);
        u64* dst = hb_g + (size_t)(((s + 1) & 1) * 4096) + mC * 256 + k * 16 + (uC >> 1);
        __hip_atomic_store(dst, val, __ATOMIC_RELAXED, __HIP_MEMORY_SCOPE_AGENT);
      }
    }

    // 11) output stores, off the critical path
    if (act) {
      const int rst = rowstart[t];
      out[(size_t)(rst + bcell) * HH + u0 + uC] = hn;
      if (t == 0) {
        out[hT_off + (size_t)bcell * HH + u0 + uC] = hn;
        out[cT_off + (size_t)bcell * HH + u0 + uC] = cn;
      }
    }
  }
}

extern "C" void kernel_launch(void* const* d_in, const int* in_sizes, int n_in,
                              void* d_out, int out_size, void* d_ws, size_t ws_size,
                              hipStream_t stream) {
  const float* X    = (const float*)d_in[0];
  const float* h0   = (const float*)d_in[1];
  const float* c0   = (const float*)d_in[2];
  const float* w_ih = (const float*)d_in[3];
  const float* w_hh = (const float*)d_in[4];
  const float* b_ih = (const float*)d_in[5];
  const float* b_hh = (const float*)d_in[6];
  const int* t_idx  = (const int*)d_in[7];
  const int* b_idx  = (const int*)d_in[8];
  int total = in_sizes[0] / DD;

  // ws layout: hbuf (16384 u64 = 128KB) | rowstart (2048 int) | L (32 int)
  u64* hbuf     = (u64*)d_ws;
  int* rowstart = (int*)((char*)d_ws + 131072);
  int* L        = rowstart + 2048;

  hipLaunchKernelGGL(init_state, dim3(64), dim3(256), 0, stream, hbuf, h0, L);
  hipLaunchKernelGGL(init_idx, dim3((total + 255) / 256), dim3(256), 0, stream,
                     t_idx, b_idx, rowstart, L, total);
  hipLaunchKernelGGL(lstm_main, dim3(32), dim3(512), 0, stream,
                     X, h0, c0, w_ih, w_hh, b_ih, b_hh, rowstart, L, hbuf,
                     (float*)d_out, total);
}

// Round 5
// 4266.130 us; speedup vs baseline: 1.7374x; 1.0598x over previous
//
#include <hip/hip_runtime.h>
#include <hip/hip_bf16.h>
#include <stdint.h>

typedef __attribute__((ext_vector_type(8))) short bf16x8;
typedef __attribute__((ext_vector_type(4))) float f32x4;
typedef __attribute__((ext_vector_type(4))) int int4v;
typedef unsigned long long u64;

#define DD 512
#define HH 512
#define BB 32

__device__ __forceinline__ unsigned short f2bf(float f) {
  unsigned u = __float_as_uint(f);
  u += 0x7fffu + ((u >> 16) & 1u);
  return (unsigned short)(u >> 16);
}
__device__ __forceinline__ int pk2(float a, float b) {
  return (int)((unsigned)f2bf(a) | ((unsigned)f2bf(b) << 16));
}
__device__ __forceinline__ float bf2f(unsigned short v) {
  return __uint_as_float((unsigned)v << 16);
}
__device__ __forceinline__ float sigf(float x) { return 1.f / (1.f + __expf(-x)); }
__device__ __forceinline__ float tanhfast(float x) {
  float e = __expf(fminf(fmaxf(2.f * x, -60.f), 60.f));
  return (e - 1.f) / (e + 1.f);
}

// ---- init kernels ----
// hbuf: u64 entries, [g(2)][parity(2)][row(16)][pair(256)]; value = tag<<32 | 2xbf16
__global__ void init_state(u64* hbuf, const float* __restrict__ h0, int* L) {
  int i = blockIdx.x * blockDim.x + threadIdx.x;
  if (i < 32) L[i] = 0;
  if (i < 16384) {
    int g = i >> 13, p = (i >> 12) & 1, m = (i >> 8) & 15, q = i & 255;
    u64 v;
    if (p == 0) {
      int b = g * 16 + m;
      unsigned lo = f2bf(h0[(size_t)b * HH + 2 * q]);
      unsigned hi = f2bf(h0[(size_t)b * HH + 2 * q + 1]);
      v = (u64)(lo | (hi << 16));              // tag = 0 (step 0)
    } else {
      v = 0xFFFFFFFF00000000ull;               // tag that never matches
    }
    hbuf[i] = v;
  }
}

__global__ void init_idx(const int* __restrict__ t_idx, const int* __restrict__ b_idx,
                         int* rowstart, int* L, int total) {
  int r = blockIdx.x * blockDim.x + threadIdx.x;
  if (r >= total) return;
  int t = t_idx[r];
  if (r == 0 || t_idx[r - 1] != t) rowstart[t] = r;
  atomicMax(&L[b_idx[r]], t + 1);
}

// ---- GX precompute: GX[r][c] = bf16( X[r,:] @ w_ih[c,:] + b_ih[c] + b_hh[c] ) ----
// tile M=64 rows x N=256 cols, K in 8 chunks of 64. grid = rtiles*8, block 256 (4 waves).
__global__ __launch_bounds__(256, 2)
void gx_gemm(const float* __restrict__ X, const float* __restrict__ w_ih,
             const float* __restrict__ b_ih, const float* __restrict__ b_hh,
             unsigned short* __restrict__ GX, int total)
{
  const int ct = blockIdx.x & 7;
  const int rt = blockIdx.x >> 3;
  const int r0 = rt * 64;
  const int j0 = ct * 256;
  const int tid = threadIdx.x;
  const int lane = tid & 63, wv = tid >> 6;
  const int ul = lane & 15, kc = lane >> 4;

  __shared__ unsigned short As[64 * 64];    // [row][K64] 8KB, swizzled
  __shared__ unsigned short Bs[256 * 64];   // [col][K64] 32KB, swizzled
  char* As_c = (char*)As;
  char* Bs_c = (char*)Bs;

  f32x4 acc[4][4];
#pragma unroll
  for (int mf = 0; mf < 4; mf++)
#pragma unroll
    for (int nf = 0; nf < 4; nf++) acc[mf][nf] = (f32x4){0.f, 0.f, 0.f, 0.f};

  const int arow_s = tid >> 2;
  const int akq = (tid & 3) * 16;
  const size_t arow_g = (size_t)min(r0 + arow_s, total - 1);
  const int ab = arow_s * 128 + akq * 2, asw = (arow_s & 7) << 4;
  const int bcol = tid;
  const int bb = bcol * 128, bsw = (bcol & 7) << 4;

  for (int ch = 0; ch < 8; ch++) {
    const int k0 = ch * 64;
    // stage A (64x64 f32 -> bf16)
    {
      const f32x4* ap = (const f32x4*)(X + arow_g * DD + k0 + akq);
      f32x4 a0 = ap[0], a1 = ap[1], a2 = ap[2], a3 = ap[3];
      int4v p0 = {pk2(a0[0], a0[1]), pk2(a0[2], a0[3]), pk2(a1[0], a1[1]), pk2(a1[2], a1[3])};
      int4v p1 = {pk2(a2[0], a2[1]), pk2(a2[2], a2[3]), pk2(a3[0], a3[1]), pk2(a3[2], a3[3])};
      *(int4v*)(As_c + (ab ^ asw)) = p0;
      *(int4v*)(As_c + ((ab + 16) ^ asw)) = p1;
    }
    // stage B (256 cols x 64 K)
    {
      const f32x4* bp = (const f32x4*)(w_ih + (size_t)(j0 + bcol) * DD + k0);
#pragma unroll
      for (int q = 0; q < 4; q++) {
        f32x4 b0 = bp[4 * q], b1 = bp[4 * q + 1], b2 = bp[4 * q + 2], b3 = bp[4 * q + 3];
        int4v p0 = {pk2(b0[0], b0[1]), pk2(b0[2], b0[3]), pk2(b1[0], b1[1]), pk2(b1[2], b1[3])};
        int4v p1 = {pk2(b2[0], b2[1]), pk2(b2[2], b2[3]), pk2(b3[0], b3[1]), pk2(b3[2], b3[3])};
        *(int4v*)(Bs_c + ((bb + q * 32) ^ bsw)) = p0;
        *(int4v*)(Bs_c + ((bb + q * 32 + 16) ^ bsw)) = p1;
      }
    }
    __syncthreads();
#pragma unroll
    for (int ks = 0; ks < 2; ks++) {
      bf16x8 bfr[4], afr[4];
#pragma unroll
      for (int nf = 0; nf < 4; nf++) {
        int col = wv * 64 + nf * 16 + ul;
        bfr[nf] = *(const bf16x8*)(Bs_c + ((col * 128 + ks * 64 + kc * 16) ^ ((col & 7) << 4)));
      }
#pragma unroll
      for (int mf = 0; mf < 4; mf++) {
        int row = mf * 16 + ul;
        afr[mf] = *(const bf16x8*)(As_c + ((row * 128 + ks * 64 + kc * 16) ^ ((row & 7) << 4)));
      }
#pragma unroll
      for (int mf = 0; mf < 4; mf++)
#pragma unroll
        for (int nf = 0; nf < 4; nf++)
          acc[mf][nf] = __builtin_amdgcn_mfma_f32_16x16x32_bf16(afr[mf], bfr[nf], acc[mf][nf], 0, 0, 0);
    }
    __syncthreads();
  }
  // epilogue: + bias, store bf16
#pragma unroll
  for (int nf = 0; nf < 4; nf++) {
    int c = j0 + wv * 64 + nf * 16 + ul;
    float bias = b_ih[c] + b_hh[c];
#pragma unroll
    for (int mf = 0; mf < 4; mf++)
#pragma unroll
      for (int r = 0; r < 4; r++) {
        int row = r0 + mf * 16 + kc * 4 + r;
        if (row < total) GX[(size_t)row * 2048 + c] = f2bf(acc[mf][nf][r] + bias);
      }
  }
}

// ---- recurrent kernel, x-part precomputed ----
// 32 blocks x 512 threads. g = bid&1, k = bid>>1 (units [32k,32k+32)).
__global__ __launch_bounds__(512, 2)
void lstm_gx(const float* __restrict__ h0, const float* __restrict__ c0,
             const float* __restrict__ w_hh,
             const int* __restrict__ rowstart, const int* __restrict__ L,
             u64* hbuf, const unsigned short* __restrict__ GX,
             float* out, int total)
{
  const int tid = threadIdx.x;
  const int bid = blockIdx.x;
  const int g = bid & 1;
  const int k = bid >> 1;
  const int lane = tid & 63;
  const int wave = tid >> 6;
  const int gate = wave & 3;
  const int cs = wave >> 2;
  const int ul = lane & 15;
  const int kc = lane >> 4;
  const int u0 = k * 32;
  const int j = gate * 512 + u0 + cs * 16 + ul;

  __shared__ unsigned short h_st[16 * HH];   // 16KB swizzled
  __shared__ float gl[4][16][33];            // padded gate exchange

  bf16x8 wfb[16];
#pragma unroll
  for (int kk = 0; kk < 16; kk++) {
    const float* pb = w_hh + (size_t)j * HH + kk * 32 + kc * 8;
    bf16x8 vb;
#pragma unroll
    for (int e = 0; e < 8; e++) vb[e] = (short)f2bf(pb[e]);
    wfb[kk] = vb;
  }

  const int mC = tid >> 5;
  const int uC = tid & 31;
  const int bcell = g * 16 + mC;
  const int uu = u0 + uC;
  const int Lc = L[bcell];
  float c_reg = c0[(size_t)bcell * HH + uu];
  const float c0c = c_reg;
  const float h0c = h0[(size_t)bcell * HH + uu];

  int t0 = 0;
#pragma unroll
  for (int m = 0; m < 16; m++) t0 = max(t0, L[g * 16 + m]);
  t0 -= 1;
  const int S = t0 + 1;

  u64* hb_g = hbuf + g * 8192;
  const size_t hT_off = (size_t)total * HH;
  const size_t cT_off = hT_off + (size_t)BB * HH;

  char* hst_c = (char*)h_st;
  const int gr = (mC + k) & 15;
  const int gc = (uC + 2 * k) & 31;
  const int hbyte = gr * 1024 + gc * 32, hsw = (gr & 7) << 4;
  const int arow = ul * 1024, aswz = (ul & 7) << 4;

  // prologue: GX for first step
  unsigned short gx0 = 0, gx1 = 0, gx2 = 0, gx3 = 0;
  if (t0 < Lc) {
    const unsigned short* gp = GX + (size_t)(rowstart[t0] + bcell) * 2048 + uu;
    gx0 = gp[0]; gx1 = gp[512]; gx2 = gp[1024]; gx3 = gp[1536];
  }

  for (int s = 0, t = t0; s < S; s++, t--) {
    const bool act = (t < Lc);
    // 1) issue tagged h-gather (doubles as sync poll)
    const u64* src = hb_g + (size_t)((s & 1) * 4096) + gr * 256 + gc * 8;
    int4v c0v, c1v, c2v, c3v;
    asm volatile(
      "global_load_dwordx4 %0, %4, off sc0 sc1\n\t"
      "global_load_dwordx4 %1, %5, off sc0 sc1\n\t"
      "global_load_dwordx4 %2, %6, off sc0 sc1\n\t"
      "global_load_dwordx4 %3, %7, off sc0 sc1"
      : "=&v"(c0v), "=&v"(c1v), "=&v"(c2v), "=&v"(c3v)
      : "v"(src), "v"(src + 2), "v"(src + 4), "v"(src + 6)
      : "memory");
    asm volatile("s_waitcnt vmcnt(0)" ::: "memory");
    __builtin_amdgcn_sched_barrier(0);
    const unsigned want = (unsigned)s;
    int spins = 0;
    while (!(((unsigned)c0v[1] == want) & ((unsigned)c0v[3] == want) &
             ((unsigned)c1v[1] == want) & ((unsigned)c1v[3] == want) &
             ((unsigned)c2v[1] == want) & ((unsigned)c2v[3] == want) &
             ((unsigned)c3v[1] == want) & ((unsigned)c3v[3] == want))) {
      if (++spins < 4096) {
        asm volatile(
          "global_load_dwordx4 %0, %4, off sc0 sc1\n\t"
          "global_load_dwordx4 %1, %5, off sc0 sc1\n\t"
          "global_load_dwordx4 %2, %6, off sc0 sc1\n\t"
          "global_load_dwordx4 %3, %7, off sc0 sc1\n\t"
          "s_waitcnt vmcnt(0)"
          : "=&v"(c0v), "=&v"(c1v), "=&v"(c2v), "=&v"(c3v)
          : "v"(src), "v"(src + 2), "v"(src + 4), "v"(src + 6)
          : "memory");
        __builtin_amdgcn_sched_barrier(0);
      } else {
        u64 a0 = __hip_atomic_load(src + 0, __ATOMIC_RELAXED, __HIP_MEMORY_SCOPE_AGENT);
        u64 a1 = __hip_atomic_load(src + 1, __ATOMIC_RELAXED, __HIP_MEMORY_SCOPE_AGENT);
        u64 a2 = __hip_atomic_load(src + 2, __ATOMIC_RELAXED, __HIP_MEMORY_SCOPE_AGENT);
        u64 a3 = __hip_atomic_load(src + 3, __ATOMIC_RELAXED, __HIP_MEMORY_SCOPE_AGENT);
        u64 a4 = __hip_atomic_load(src + 4, __ATOMIC_RELAXED, __HIP_MEMORY_SCOPE_AGENT);
        u64 a5 = __hip_atomic_load(src + 5, __ATOMIC_RELAXED, __HIP_MEMORY_SCOPE_AGENT);
        u64 a6 = __hip_atomic_load(src + 6, __ATOMIC_RELAXED, __HIP_MEMORY_SCOPE_AGENT);
        u64 a7 = __hip_atomic_load(src + 7, __ATOMIC_RELAXED, __HIP_MEMORY_SCOPE_AGENT);
        c0v = (int4v){(int)a0, (int)(a0 >> 32), (int)a1, (int)(a1 >> 32)};
        c1v = (int4v){(int)a2, (int)(a2 >> 32), (int)a3, (int)(a3 >> 32)};
        c2v = (int4v){(int)a4, (int)(a4 >> 32), (int)a5, (int)(a5 >> 32)};
        c3v = (int4v){(int)a6, (int)(a6 >> 32), (int)a7, (int)(a7 >> 32)};
      }
    }

    // 2) stage h -> swizzled LDS (strip tags)
    {
      int4v d0 = {c0v[0], c0v[2], c1v[0], c1v[2]};
      int4v d1 = {c2v[0], c2v[2], c3v[0], c3v[2]};
      *(int4v*)(hst_c + (hbyte ^ hsw)) = d0;
      *(int4v*)(hst_c + ((hbyte + 16) ^ hsw)) = d1;
    }
    // 3) prefetch next step's GX (tiny; lands during MFMA/cell)
    unsigned short ngx0 = 0, ngx1 = 0, ngx2 = 0, ngx3 = 0;
    if (t > 0 && (t - 1) < Lc) {
      const unsigned short* gp = GX + (size_t)(rowstart[t - 1] + bcell) * 2048 + uu;
      ngx0 = gp[0]; ngx1 = gp[512]; ngx2 = gp[1024]; ngx3 = gp[1536];
    }
    __syncthreads();   // B2: h_st ready

    // 4) h-part MFMAs, two chains
    f32x4 C = {0.f, 0.f, 0.f, 0.f};
    f32x4 C2 = {0.f, 0.f, 0.f, 0.f};
#pragma unroll
    for (int kk = 0; kk < 8; kk++) {
      bf16x8 A0 = *(const bf16x8*)(hst_c + ((arow + (2 * kk) * 64 + kc * 16) ^ aswz));
      bf16x8 A1 = *(const bf16x8*)(hst_c + ((arow + (2 * kk + 1) * 64 + kc * 16) ^ aswz));
      C  = __builtin_amdgcn_mfma_f32_16x16x32_bf16(A0, wfb[2 * kk], C, 0, 0, 0);
      C2 = __builtin_amdgcn_mfma_f32_16x16x32_bf16(A1, wfb[2 * kk + 1], C2, 0, 0, 0);
    }
    // 5) exchange gates (C/D layout: col=lane&15, row=(lane>>4)*4+r)
#pragma unroll
    for (int r = 0; r < 4; r++) gl[gate][kc * 4 + r][cs * 16 + ul] = C[r] + C2[r];
    __syncthreads();   // B3

    // 6) cell math (fp32, c thread-resident), gx folded in
    float gi = gl[0][mC][uC] + bf2f(gx0);
    float gf = gl[1][mC][uC] + bf2f(gx1);
    float gg = gl[2][mC][uC] + bf2f(gx2);
    float go = gl[3][mC][uC] + bf2f(gx3);
    float iv = sigf(gi), fv = sigf(gf), gv = tanhfast(gg), ov = sigf(go);
    float cn = fv * c_reg + iv * gv;
    float hn = ov * tanhfast(cn);
    float hp = act ? hn : h0c;
    c_reg = act ? cn : c0c;

    // 7) publish tagged pairs immediately
    {
      unsigned hbf = (unsigned)f2bf(hp);
      unsigned v1 = __shfl_down(hbf, 1);
      if ((uC & 1) == 0) {
        u64 val = ((u64)(unsigned)(s + 1) << 32) | (hbf & 0xffffu) | ((v1 & 0xffffu) << 16);
        u64* dst = hb_g + (size_t)(((s + 1) & 1) * 4096) + mC * 256 + k * 16 + (uC >> 1);
        __hip_atomic_store(dst, val, __ATOMIC_RELAXED, __HIP_MEMORY_SCOPE_AGENT);
      }
    }
    // 8) output stores
    if (act) {
      const int rst = rowstart[t];
      out[(size_t)(rst + bcell) * HH + uu] = hn;
      if (t == 0) {
        out[hT_off + (size_t)bcell * HH + uu] = hn;
        out[cT_off + (size_t)bcell * HH + uu] = cn;
      }
    }
    gx0 = ngx0; gx1 = ngx1; gx2 = ngx2; gx3 = ngx3;
  }
}

// ---- fallback: round-4 fused kernel (used when ws too small for GX) ----
__global__ __launch_bounds__(512, 2)
void lstm_fused(const float* __restrict__ X, const float* __restrict__ h0,
                const float* __restrict__ c0, const float* __restrict__ w_ih,
                const float* __restrict__ w_hh, const float* __restrict__ b_ih,
                const float* __restrict__ b_hh, const int* __restrict__ rowstart,
                const int* __restrict__ L, u64* hbuf,
                float* out, int total)
{
  const int tid = threadIdx.x;
  const int bid = blockIdx.x;
  const int g = bid & 1;
  const int k = bid >> 1;
  const int lane = tid & 63;
  const int wave = tid >> 6;
  const int gate = wave & 3;
  const int cs = wave >> 2;
  const int ul = lane & 15;
  const int kc = lane >> 4;
  const int u0 = k * 32;
  const int j = gate * 512 + u0 + cs * 16 + ul;

  __shared__ unsigned short h_st[16 * DD];
  __shared__ unsigned short x_st[16 * DD];
  __shared__ float gl[4][16][32];

  bf16x8 wfa[16], wfb[16];
#pragma unroll
  for (int kk = 0; kk < 16; kk++) {
    const float* pa = w_ih + (size_t)j * DD + kk * 32 + kc * 8;
    const float* pb = w_hh + (size_t)j * DD + kk * 32 + kc * 8;
    bf16x8 va, vb;
#pragma unroll
    for (int e = 0; e < 8; e++) { va[e] = (short)f2bf(pa[e]); vb[e] = (short)f2bf(pb[e]); }
    wfa[kk] = va; wfb[kk] = vb;
  }
  const float bias = b_ih[j] + b_hh[j];

  const int mC = tid >> 5;
  const int uC = tid & 31;
  const int bcell = g * 16 + mC;
  const int Lc = L[bcell];
  float c_reg = c0[(size_t)bcell * HH + u0 + uC];
  const float c0c = c_reg;
  const float h0c = h0[(size_t)bcell * HH + u0 + uC];

  int t0 = 0;
#pragma unroll
  for (int m = 0; m < 16; m++) t0 = max(t0, L[g * 16 + m]);
  t0 -= 1;
  const int S = t0 + 1;

  u64* hb_g = hbuf + g * 8192;
  const size_t hT_off = (size_t)total * HH;
  const size_t cT_off = hT_off + (size_t)BB * HH;

  char* hst_c = (char*)h_st;
  char* xst_c = (char*)x_st;
  const int gr = (mC + k) & 15;
  const int gc = (uC + 2 * k) & 31;
  const int hbyte = gr * 1024 + gc * 32, hsw = (gr & 7) << 4;
  const int xbyte = mC * 1024 + uC * 32, xsw = (mC & 7) << 4;
  const int arow = ul * 1024, aswz = (ul & 7) << 4;

  f32x4 xr[4];
  {
    if (t0 < Lc) {
      const f32x4* xp = (const f32x4*)(X + (size_t)(rowstart[t0] + bcell) * DD + uC * 16);
#pragma unroll
      for (int q = 0; q < 4; q++) xr[q] = xp[q];
    } else {
#pragma unroll
      for (int q = 0; q < 4; q++) xr[q] = (f32x4){0.f, 0.f, 0.f, 0.f};
    }
  }

  for (int s = 0, t = t0; s < S; s++, t--) {
    const bool act = (t < Lc);
    {
      int4v e0 = {pk2(xr[0][0], xr[0][1]), pk2(xr[0][2], xr[0][3]),
                  pk2(xr[1][0], xr[1][1]), pk2(xr[1][2], xr[1][3])};
      int4v e1 = {pk2(xr[2][0], xr[2][1]), pk2(xr[2][2], xr[2][3]),
                  pk2(xr[3][0], xr[3][1]), pk2(xr[3][2], xr[3][3])};
      *(int4v*)(xst_c + (xbyte ^ xsw)) = e0;
      *(int4v*)(xst_c + ((xbyte + 16) ^ xsw)) = e1;
    }
    __syncthreads();

    const u64* src = hb_g + (size_t)((s & 1) * 4096) + gr * 256 + gc * 8;
    int4v c0v, c1v, c2v, c3v;
    asm volatile(
      "global_load_dwordx4 %0, %4, off sc0 sc1\n\t"
      "global_load_dwordx4 %1, %5, off sc0 sc1\n\t"
      "global_load_dwordx4 %2, %6, off sc0 sc1\n\t"
      "global_load_dwordx4 %3, %7, off sc0 sc1"
      : "=&v"(c0v), "=&v"(c1v), "=&v"(c2v), "=&v"(c3v)
      : "v"(src), "v"(src + 2), "v"(src + 4), "v"(src + 6)
      : "memory");

    f32x4 C = {bias, bias, bias, bias};
#pragma unroll
    for (int kk = 0; kk < 16; kk++) {
      bf16x8 A = *(const bf16x8*)(xst_c + ((arow + kk * 64 + kc * 16) ^ aswz));
      C = __builtin_amdgcn_mfma_f32_16x16x32_bf16(A, wfa[kk], C, 0, 0, 0);
    }

    asm volatile("s_waitcnt vmcnt(0)" ::: "memory");
    __builtin_amdgcn_sched_barrier(0);
    const unsigned want = (unsigned)s;
    int spins = 0;
    while (!(((unsigned)c0v[1] == want) & ((unsigned)c0v[3] == want) &
             ((unsigned)c1v[1] == want) & ((unsigned)c1v[3] == want) &
             ((unsigned)c2v[1] == want) & ((unsigned)c2v[3] == want) &
             ((unsigned)c3v[1] == want) & ((unsigned)c3v[3] == want))) {
      if (++spins < 4096) {
        asm volatile(
          "global_load_dwordx4 %0, %4, off sc0 sc1\n\t"
          "global_load_dwordx4 %1, %5, off sc0 sc1\n\t"
          "global_load_dwordx4 %2, %6, off sc0 sc1\n\t"
          "global_load_dwordx4 %3, %7, off sc0 sc1\n\t"
          "s_waitcnt vmcnt(0)"
          : "=&v"(c0v), "=&v"(c1v), "=&v"(c2v), "=&v"(c3v)
          : "v"(src), "v"(src + 2), "v"(src + 4), "v"(src + 6)
          : "memory");
        __builtin_amdgcn_sched_barrier(0);
      } else {
        u64 a0 = __hip_atomic_load(src + 0, __ATOMIC_RELAXED, __HIP_MEMORY_SCOPE_AGENT);
        u64 a1 = __hip_atomic_load(src + 1, __ATOMIC_RELAXED, __HIP_MEMORY_SCOPE_AGENT);
        u64 a2 = __hip_atomic_load(src + 2, __ATOMIC_RELAXED, __HIP_MEMORY_SCOPE_AGENT);
        u64 a3 = __hip_atomic_load(src + 3, __ATOMIC_RELAXED, __HIP_MEMORY_SCOPE_AGENT);
        u64 a4 = __hip_atomic_load(src + 4, __ATOMIC_RELAXED, __HIP_MEMORY_SCOPE_AGENT);
        u64 a5 = __hip_atomic_load(src + 5, __ATOMIC_RELAXED, __HIP_MEMORY_SCOPE_AGENT);
        u64 a6 = __hip_atomic_load(src + 6, __ATOMIC_RELAXED, __HIP_MEMORY_SCOPE_AGENT);
        u64 a7 = __hip_atomic_load(src + 7, __ATOMIC_RELAXED, __HIP_MEMORY_SCOPE_AGENT);
        c0v = (int4v){(int)a0, (int)(a0 >> 32), (int)a1, (int)(a1 >> 32)};
        c1v = (int4v){(int)a2, (int)(a2 >> 32), (int)a3, (int)(a3 >> 32)};
        c2v = (int4v){(int)a4, (int)(a4 >> 32), (int)a5, (int)(a5 >> 32)};
        c3v = (int4v){(int)a6, (int)(a6 >> 32), (int)a7, (int)(a7 >> 32)};
      }
    }

    {
      bool nact = false;
      if (t > 0) {
        nact = ((t - 1) < Lc);
        if (nact) {
          const f32x4* xp = (const f32x4*)(X + (size_t)(rowstart[t - 1] + bcell) * DD + uC * 16);
#pragma unroll
          for (int q = 0; q < 4; q++) xr[q] = xp[q];
        }
      }
      if (!nact) {
#pragma unroll
        for (int q = 0; q < 4; q++) xr[q] = (f32x4){0.f, 0.f, 0.f, 0.f};
      }
    }

    {
      int4v d0 = {c0v[0], c0v[2], c1v[0], c1v[2]};
      int4v d1 = {c2v[0], c2v[2], c3v[0], c3v[2]};
      *(int4v*)(hst_c + (hbyte ^ hsw)) = d0;
      *(int4v*)(hst_c + ((hbyte + 16) ^ hsw)) = d1;
    }
    __syncthreads();

    f32x4 C2 = {0.f, 0.f, 0.f, 0.f};
#pragma unroll
    for (int kk = 0; kk < 8; kk++) {
      bf16x8 A0 = *(const bf16x8*)(hst_c + ((arow + (2 * kk) * 64 + kc * 16) ^ aswz));
      bf16x8 A1 = *(const bf16x8*)(hst_c + ((arow + (2 * kk + 1) * 64 + kc * 16) ^ aswz));
      C  = __builtin_amdgcn_mfma_f32_16x16x32_bf16(A0, wfb[2 * kk], C, 0, 0, 0);
      C2 = __builtin_amdgcn_mfma_f32_16x16x32_bf16(A1, wfb[2 * kk + 1], C2, 0, 0, 0);
    }
#pragma unroll
    for (int r = 0; r < 4; r++) C[r] += C2[r];

#pragma unroll
    for (int r = 0; r < 4; r++) gl[gate][kc * 4 + r][cs * 16 + ul] = C[r];
    __syncthreads();

    float gi = gl[0][mC][uC], gf = gl[1][mC][uC], gg = gl[2][mC][uC], go = gl[3][mC][uC];
    float iv = sigf(gi), fv = sigf(gf), gv = tanhfast(gg), ov = sigf(go);
    float cn = fv * c_reg + iv * gv;
    float hn = ov * tanhfast(cn);
    float hp = act ? hn : h0c;
    c_reg = act ? cn : c0c;

    {
      unsigned hbf = (unsigned)f2bf(hp);
      unsigned v1 = __shfl_down(hbf, 1);
      if ((uC & 1) == 0) {
        u64 val = ((u64)(unsigned)(s + 1) << 32) | (hbf & 0xffffu) | ((v1 & 0xffffu) << 16);
        u64* dst = hb_g + (size_t)(((s + 1) & 1) * 4096) + mC * 256 + k * 16 + (uC >> 1);
        __hip_atomic_store(dst, val, __ATOMIC_RELAXED, __HIP_MEMORY_SCOPE_AGENT);
      }
    }

    if (act) {
      const int rst = rowstart[t];
      out[(size_t)(rst + bcell) * HH + u0 + uC] = hn;
      if (t == 0) {
        out[hT_off + (size_t)bcell * HH + u0 + uC] = hn;
        out[cT_off + (size_t)bcell * HH + u0 + uC] = cn;
      }
    }
  }
}

extern "C" void kernel_launch(void* const* d_in, const int* in_sizes, int n_in,
                              void* d_out, int out_size, void* d_ws, size_t ws_size,
                              hipStream_t stream) {
  const float* X    = (const float*)d_in[0];
  const float* h0   = (const float*)d_in[1];
  const float* c0   = (const float*)d_in[2];
  const float* w_ih = (const float*)d_in[3];
  const float* w_hh = (const float*)d_in[4];
  const float* b_ih = (const float*)d_in[5];
  const float* b_hh = (const float*)d_in[6];
  const int* t_idx  = (const int*)d_in[7];
  const int* b_idx  = (const int*)d_in[8];
  int total = in_sizes[0] / DD;

  // ws layout: hbuf (16384 u64 = 128KB) | rowstart (2048 int) | L (32 int) | GX
  u64* hbuf     = (u64*)d_ws;
  int* rowstart = (int*)((char*)d_ws + 131072);
  int* L        = rowstart + 2048;
  const size_t GX_OFF = 147456;
  unsigned short* GX = (unsigned short*)((char*)d_ws + GX_OFF);
  const size_t need = GX_OFF + (size_t)total * 2048 * 2;

  hipLaunchKernelGGL(init_state, dim3(64), dim3(256), 0, stream, hbuf, h0, L);
  hipLaunchKernelGGL(init_idx, dim3((total + 255) / 256), dim3(256), 0, stream,
                     t_idx, b_idx, rowstart, L, total);
  if (ws_size >= need) {
    int rt = (total + 63) >> 6;
    hipLaunchKernelGGL(gx_gemm, dim3(rt * 8), dim3(256), 0, stream,
                       X, w_ih, b_ih, b_hh, GX, total);
    hipLaunchKernelGGL(lstm_gx, dim3(32), dim3(512), 0, stream,
                       h0, c0, w_hh, rowstart, L, hbuf, GX, (float*)d_out, total);
  } else {
    hipLaunchKernelGGL(lstm_fused, dim3(32), dim3(512), 0, stream,
                       X, h0, c0, w_ih, w_hh, b_ih, b_hh, rowstart, L, hbuf,
                       (float*)d_out, total);
  }
}